// Round 7
// baseline (253.609 us; speedup 1.0000x reference)
//
#include <hip/hip_runtime.h>
#include <hip/hip_cooperative_groups.h>

namespace cg = cooperative_groups;

#define NEG_SLOPE_F 0.2f

static constexpr int Nn = 4096;   // nodes
static constexpr int Tt = 3;      // edge types
static constexpr int Dd = 16;     // emb dim
static constexpr int Hh = 4;      // heads
static constexpr int CAP = 256;   // max distinct neighbors per row (E[deg]≈96)
static constexpr int WPR = 128;   // 32-bit words per row per type (4096/32)
static constexpr int NBLK = 1024; // 4 rows/block in phase 2

__device__ __forceinline__ float waveMax(float v) {
#pragma unroll
  for (int m = 1; m < 64; m <<= 1) v = fmaxf(v, __shfl_xor(v, m));
  return v;
}
__device__ __forceinline__ float waveSum(float v) {
#pragma unroll
  for (int m = 1; m < 64; m <<= 1) v += __shfl_xor(v, m);
  return v;
}

// One cooperative kernel: clear+prep | atomics | per-row softmax.
__global__ void __launch_bounds__(256, 4) fused_kernel(
    const float* __restrict__ scores, const float* __restrict__ emb,
    const float* __restrict__ attw, const int* __restrict__ el, int E,
    unsigned int* __restrict__ bitmap, float* __restrict__ pv,
    float* __restrict__ out) {
  cg::grid_group grid = cg::this_grid();
  __shared__ unsigned short lst[4][CAP];  // 2 KiB (phase 2)
  __shared__ float rb[4];                 // (phase 0, block 0)
  int tid = threadIdx.x, bid = blockIdx.x;

  // ---- phase 0: zero the 6 MB bitmap; block 0 computes pv ----
  {
    uint4* bm4 = (uint4*)bitmap;
    const int total4 = Nn * 3 * WPR / 4;  // 393216
    uint4 z = make_uint4(0u, 0u, 0u, 0u);
    for (int k = bid * 256 + tid; k < total4; k += NBLK * 256) bm4[k] = z;
    if (bid == 0) {
      float s = 0.f;
      for (int j = tid; j < Nn; j += 256) s += scores[j];
      s = waveSum(s);
      if ((tid & 63) == 0) rb[tid >> 6] = s;
      __syncthreads();
      if (tid == 0) pv[12] = rb[0] + rb[1] + rb[2] + rb[3];
      if (tid < Hh * Tt) {
        int h = tid / Tt, t = tid % Tt;
        float c = 0.f;
#pragma unroll
        for (int d = 0; d < Dd; ++d)
          c += emb[t * Dd + d] * attw[h * (Dd + 2) + 1 + d];
        pv[tid] = c;
      }
    }
  }
  grid.sync();

  // ---- phase 1: fire-and-forget bit atomicOr, both directions ----
  {
    int nE = Tt * E;
    for (int k = bid * 256 + tid; k < nE; k += NBLK * 256) {
      int t = k / E, e = k - t * E;
      unsigned int a = (unsigned int)el[(t * 2 + 0) * E + e];
      unsigned int b = (unsigned int)el[(t * 2 + 1) * E + e];
      atomicOr(&bitmap[(a * 3u + t) * WPR + (b >> 5)], 1u << (b & 31u));
      atomicOr(&bitmap[(b * 3u + t) * WPR + (a >> 5)], 1u << (a & 31u));
    }
  }
  grid.sync();

  // ---- phase 2: one wave per row — extract packed (j|m<<12) list, softmax ----
  int wid = tid >> 6, lane = tid & 63;
  int i = bid * 4 + wid;
  const unsigned int* bm = bitmap + (size_t)i * 3 * WPR;

  unsigned int w[2][3];
#pragma unroll
  for (int p = 0; p < 2; ++p)
#pragma unroll
    for (int t = 0; t < 3; ++t) w[p][t] = bm[t * WPR + p * 64 + lane];
  unsigned int orw[2];
  orw[0] = w[0][0] | w[0][1] | w[0][2];
  orw[1] = w[1][0] | w[1][1] | w[1][2];
  int c = __popc(orw[0]) + __popc(orw[1]);
  int off = c;
#pragma unroll
  for (int d = 1; d < 64; d <<= 1) {
    int tv = __shfl_up(off, d);
    if (lane >= d) off += tv;
  }
  int n = __shfl(off, 63);  // row degree (distinct neighbors)
  off -= c;                 // exclusive
  if (n > CAP) n = CAP;
  int idx = off;
#pragma unroll
  for (int p = 0; p < 2; ++p) {
    unsigned int o = orw[p];
    int jbase = (p * 64 + lane) * 32;
    while (o) {
      int b = __ffs(o) - 1;
      o &= o - 1;
      unsigned int m = ((w[p][0] >> b) & 1u) | (((w[p][1] >> b) & 1u) << 1) |
                       (((w[p][2] >> b) & 1u) << 2);
      if (idx < CAP) lst[wid][idx] = (unsigned short)((jbase + b) | (m << 12));
      ++idx;
    }
  }
  __syncthreads();

  float si = scores[i];
  float wsrc[Hh], wtgt[Hh], c0[Hh], c1[Hh], c2[Hh];
#pragma unroll
  for (int h = 0; h < Hh; ++h) {
    wsrc[h] = attw[h * (Dd + 2) + 0];
    wtgt[h] = attw[h * (Dd + 2) + Dd + 1];
    c0[h] = pv[h * 3 + 0];
    c1[h] = pv[h * 3 + 1];
    c2[h] = pv[h * 3 + 2];
  }
  float Ssum = pv[12];

  constexpr int IT = CAP / 64;  // 4
  float lv[IT][Hh], sjv[IT];
  float mx[Hh];
#pragma unroll
  for (int h = 0; h < Hh; ++h) mx[h] = -INFINITY;
  float sedge = 0.f;

#pragma unroll
  for (int it = 0; it < IT; ++it) {
    if (it * 64 >= n) break;  // wave-uniform early-out
    int k = it * 64 + lane;
    bool act = k < n;
    unsigned int v = act ? (unsigned int)lst[wid][k] : 0u;
    int j = (int)(v & 0xFFFu);
    int m = act ? (int)(v >> 12) : 0;
    float sj = act ? scores[j] : 0.f;
    sjv[it] = sj;
    if (act) sedge += sj;
    float na = (float)__popc(m);
    float et0 = (m & 1) ? 1.f : 0.f;
    float et1 = (m & 2) ? 1.f : 0.f;
    float et2 = (m & 4) ? 1.f : 0.f;
#pragma unroll
    for (int h = 0; h < Hh; ++h) {
      float et = et0 * c0[h] + et1 * c1[h] + et2 * c2[h];
      float l = na * (wsrc[h] * si + wtgt[h] * sj) + et;
      l = (l >= 0.f) ? l : NEG_SLOPE_F * l;
      lv[it][h] = act ? l : -INFINITY;
      mx[h] = fmaxf(mx[h], lv[it][h]);
    }
  }

#pragma unroll
  for (int h = 0; h < Hh; ++h) {
    mx[h] = waveMax(mx[h]);
    if (n < Nn) mx[h] = fmaxf(mx[h], 0.f);  // non-edge cells contribute logit 0
  }

  float se[Hh], ss[Hh];
#pragma unroll
  for (int h = 0; h < Hh; ++h) { se[h] = 0.f; ss[h] = 0.f; }
#pragma unroll
  for (int it = 0; it < IT; ++it) {
    if (it * 64 >= n) break;
#pragma unroll
    for (int h = 0; h < Hh; ++h) {
      float ex = expf(lv[it][h] - mx[h]);  // inactive lanes: exp(-inf)=0
      se[h] += ex;
      ss[h] += ex * sjv[it];
    }
  }
  sedge = waveSum(sedge);
#pragma unroll
  for (int h = 0; h < Hh; ++h) {
    se[h] = waveSum(se[h]);
    ss[h] = waveSum(ss[h]);
  }
  if (lane == 0) {
    float acc = 0.f;
#pragma unroll
    for (int h = 0; h < Hh; ++h) {
      float nz = expf(-mx[h]);  // exp(0 - max) for every non-edge cell
      float denom = se[h] + nz * ((float)Nn - (float)n);
      float numer = ss[h] + nz * (Ssum - sedge);
      acc += numer / denom;
    }
    out[i] = acc * (1.f / (float)Hh);
  }
}

extern "C" void kernel_launch(void* const* d_in, const int* in_sizes, int n_in,
                              void* d_out, int out_size, void* d_ws, size_t ws_size,
                              hipStream_t stream) {
  const float* scores = (const float*)d_in[0];
  const float* emb    = (const float*)d_in[1];
  const float* attw   = (const float*)d_in[2];
  const int*   el     = (const int*)d_in[3];
  float* out = (float*)d_out;
  int E = in_sizes[3] / (Tt * 2);

  // ws layout: [bitmap 6MB][pv 64B]
  size_t bm_bytes = (size_t)Nn * 3 * WPR * 4;  // 6 MiB
  unsigned int* bitmap = (unsigned int*)d_ws;
  float* pv = (float*)((char*)d_ws + bm_bytes);

  void* args[] = {(void*)&scores, (void*)&emb, (void*)&attw, (void*)&el,
                  (void*)&E,      (void*)&bitmap, (void*)&pv, (void*)&out};
  hipLaunchCooperativeKernel((void*)fused_kernel, dim3(NBLK), dim3(256), args,
                             0, stream);
}

// Round 8
// 41.645 us; speedup vs baseline: 6.0897x; 6.0897x over previous
//
#include <hip/hip_runtime.h>

#define NEG_SLOPE_F 0.2f

static constexpr int Nn = 4096;   // nodes
static constexpr int Tt = 3;      // edge types
static constexpr int Dd = 16;     // emb dim
static constexpr int Hh = 4;      // heads
static constexpr int CAP = 256;   // distinct-neighbor cap per row (union over types; E[.]≈96)
static constexpr int BCAP = 96;   // per-(row,type) bucket capacity incl. duplicates (Poisson λ=32)

__device__ __forceinline__ float waveMax(float v) {
#pragma unroll
  for (int m = 1; m < 64; m <<= 1) v = fmaxf(v, __shfl_xor(v, m));
  return v;
}
__device__ __forceinline__ float waveSum(float v) {
#pragma unroll
  for (int m = 1; m < 64; m <<= 1) v += __shfl_xor(v, m);
  return v;
}

// ---- kernel 1: clear the 12288 bucket counters; block 0 computes pv ----
__global__ void clear_prep_kernel(unsigned int* __restrict__ cnt,
                                  const float* __restrict__ scores,
                                  const float* __restrict__ emb,
                                  const float* __restrict__ attw,
                                  float* __restrict__ pv) {
  int tid = threadIdx.x;
  int g = blockIdx.x * 256 + tid;
  if (g < Nn * Tt) cnt[g] = 0u;
  if (blockIdx.x == 0) {
    __shared__ float rb[4];
    float s = 0.f;
    for (int j = tid; j < Nn; j += 256) s += scores[j];
    s = waveSum(s);
    if ((tid & 63) == 0) rb[tid >> 6] = s;
    __syncthreads();
    if (tid == 0) pv[12] = rb[0] + rb[1] + rb[2] + rb[3];
    if (tid < Hh * Tt) {
      int h = tid / Tt, t = tid % Tt;
      float c = 0.f;
#pragma unroll
      for (int d = 0; d < Dd; ++d)
        c += emb[t * Dd + d] * attw[h * (Dd + 2) + 1 + d];
      pv[tid] = c;
    }
  }
}

// ---- kernel 2: scatter WITH duplicates into fixed-capacity (row,type) buckets.
// Hot 48KB counter array (fast atomics) instead of 6MB random-line bitmap RMW. ----
__global__ void scatter_kernel(const int* __restrict__ el,
                               unsigned int* __restrict__ cnt,
                               unsigned short* __restrict__ slots, int E) {
  int k = blockIdx.x * blockDim.x + threadIdx.x;
  if (k >= Tt * E) return;
  int t = k / E, e = k - t * E;
  unsigned int a = (unsigned int)el[(t * 2 + 0) * E + e];
  unsigned int b = (unsigned int)el[(t * 2 + 1) * E + e];
  unsigned int pa = atomicAdd(&cnt[a * Tt + t], 1u);
  if (pa < BCAP) slots[(a * Tt + t) * BCAP + pa] = (unsigned short)b;
  unsigned int pb = atomicAdd(&cnt[b * Tt + t], 1u);
  if (pb < BCAP) slots[(b * Tt + t) * BCAP + pb] = (unsigned short)a;
}

// ---- kernel 3: one wave per row — LDS-bitmap dedup of bucket entries, then
// canonical-order extraction + analytic sparse softmax (proven path). ----
__launch_bounds__(256)
__global__ void row_kernel(const unsigned int* __restrict__ cnt,
                           const unsigned short* __restrict__ slots,
                           const float* __restrict__ scores,
                           const float* __restrict__ attw,
                           const float* __restrict__ pv,
                           float* __restrict__ out) {
  __shared__ unsigned int bmL[4][Tt * 128];   // 4 waves x 384 words = 6 KiB
  __shared__ unsigned short lst[4][CAP];      // 2 KiB
  int wid = threadIdx.x >> 6, lane = threadIdx.x & 63;
  int i = blockIdx.x * 4 + wid;
  unsigned int* bm = bmL[wid];

  // clear this wave's private bitmap (384 words, 6 per lane)
  for (int q = lane; q < Tt * 128; q += 64) bm[q] = 0u;

  int cv[Tt];
#pragma unroll
  for (int t = 0; t < Tt; ++t) {
    int c = (int)cnt[i * Tt + t];
    cv[t] = c < BCAP ? c : BCAP;
  }
  // dedup: LDS atomicOr (fire-and-forget; duplicates collapse; order-free)
  const unsigned short* sl = slots + (size_t)i * Tt * BCAP;  // 576B contiguous
  for (int k = lane; k < Tt * BCAP; k += 64) {
    int t = k / BCAP, s = k - t * BCAP;
    if (s < cv[t]) {
      unsigned int j = (unsigned int)sl[k];
      atomicOr(&bm[t * 128 + (j >> 5)], 1u << (j & 31u));
    }
  }
  __syncthreads();  // bitmap writes -> reads (cheap, uniform)

  // canonical extraction: identical to the proven round-6 path, LDS-sourced
  unsigned int w[2][3];
#pragma unroll
  for (int p = 0; p < 2; ++p)
#pragma unroll
    for (int t = 0; t < 3; ++t) w[p][t] = bm[t * 128 + p * 64 + lane];
  unsigned int orw[2];
  orw[0] = w[0][0] | w[0][1] | w[0][2];
  orw[1] = w[1][0] | w[1][1] | w[1][2];
  int c = __popc(orw[0]) + __popc(orw[1]);
  int off = c;
#pragma unroll
  for (int d = 1; d < 64; d <<= 1) {
    int tv = __shfl_up(off, d);
    if (lane >= d) off += tv;
  }
  int n = __shfl(off, 63);  // distinct neighbors in row
  off -= c;                 // exclusive
  if (n > CAP) n = CAP;
  int idx = off;
#pragma unroll
  for (int p = 0; p < 2; ++p) {
    unsigned int o = orw[p];
    int jbase = (p * 64 + lane) * 32;
    while (o) {
      int b = __ffs(o) - 1;
      o &= o - 1;
      unsigned int m = ((w[p][0] >> b) & 1u) | (((w[p][1] >> b) & 1u) << 1) |
                       (((w[p][2] >> b) & 1u) << 2);
      if (idx < CAP) lst[wid][idx] = (unsigned short)((jbase + b) | (m << 12));
      ++idx;
    }
  }
  __syncthreads();

  float si = scores[i];
  float wsrc[Hh], wtgt[Hh], c0[Hh], c1[Hh], c2[Hh];
#pragma unroll
  for (int h = 0; h < Hh; ++h) {
    wsrc[h] = attw[h * (Dd + 2) + 0];
    wtgt[h] = attw[h * (Dd + 2) + Dd + 1];
    c0[h] = pv[h * 3 + 0];
    c1[h] = pv[h * 3 + 1];
    c2[h] = pv[h * 3 + 2];
  }
  float Ssum = pv[12];

  constexpr int IT = CAP / 64;  // 4
  float lv[IT][Hh], sjv[IT];
  float mx[Hh];
#pragma unroll
  for (int h = 0; h < Hh; ++h) mx[h] = -INFINITY;
  float sedge = 0.f;

#pragma unroll
  for (int it = 0; it < IT; ++it) {
    if (it * 64 >= n) break;  // wave-uniform early-out
    int k = it * 64 + lane;
    bool act = k < n;
    unsigned int v = act ? (unsigned int)lst[wid][k] : 0u;
    int j = (int)(v & 0xFFFu);
    int m = act ? (int)(v >> 12) : 0;
    float sj = act ? scores[j] : 0.f;
    sjv[it] = sj;
    if (act) sedge += sj;
    float na = (float)__popc(m);
    float et0 = (m & 1) ? 1.f : 0.f;
    float et1 = (m & 2) ? 1.f : 0.f;
    float et2 = (m & 4) ? 1.f : 0.f;
#pragma unroll
    for (int h = 0; h < Hh; ++h) {
      float et = et0 * c0[h] + et1 * c1[h] + et2 * c2[h];
      float l = na * (wsrc[h] * si + wtgt[h] * sj) + et;
      l = (l >= 0.f) ? l : NEG_SLOPE_F * l;
      lv[it][h] = act ? l : -INFINITY;
      mx[h] = fmaxf(mx[h], lv[it][h]);
    }
  }

#pragma unroll
  for (int h = 0; h < Hh; ++h) {
    mx[h] = waveMax(mx[h]);
    if (n < Nn) mx[h] = fmaxf(mx[h], 0.f);  // non-edge cells contribute logit 0
  }

  float se[Hh], ss[Hh];
#pragma unroll
  for (int h = 0; h < Hh; ++h) { se[h] = 0.f; ss[h] = 0.f; }
#pragma unroll
  for (int it = 0; it < IT; ++it) {
    if (it * 64 >= n) break;
#pragma unroll
    for (int h = 0; h < Hh; ++h) {
      float ex = expf(lv[it][h] - mx[h]);  // inactive lanes: exp(-inf)=0
      se[h] += ex;
      ss[h] += ex * sjv[it];
    }
  }
  sedge = waveSum(sedge);
#pragma unroll
  for (int h = 0; h < Hh; ++h) {
    se[h] = waveSum(se[h]);
    ss[h] = waveSum(ss[h]);
  }
  if (lane == 0) {
    float acc = 0.f;
#pragma unroll
    for (int h = 0; h < Hh; ++h) {
      float nz = expf(-mx[h]);  // exp(0 - max) for every non-edge cell
      float denom = se[h] + nz * ((float)Nn - (float)n);
      float numer = ss[h] + nz * (Ssum - sedge);
      acc += numer / denom;
    }
    out[i] = acc * (1.f / (float)Hh);
  }
}

extern "C" void kernel_launch(void* const* d_in, const int* in_sizes, int n_in,
                              void* d_out, int out_size, void* d_ws, size_t ws_size,
                              hipStream_t stream) {
  const float* scores = (const float*)d_in[0];
  const float* emb    = (const float*)d_in[1];
  const float* attw   = (const float*)d_in[2];
  const int*   el     = (const int*)d_in[3];
  float* out = (float*)d_out;
  int E = in_sizes[3] / (Tt * 2);

  // ws layout: [cnt 48KB][pv 64B][slots 2.25MB]
  unsigned int* cnt = (unsigned int*)d_ws;
  float* pv = (float*)((char*)d_ws + (size_t)Nn * Tt * 4);
  unsigned short* slots = (unsigned short*)((char*)pv + 64);

  clear_prep_kernel<<<(Nn * Tt + 255) / 256, 256, 0, stream>>>(cnt, scores, emb,
                                                               attw, pv);
  scatter_kernel<<<(Tt * (E) + 255) / 256, 256, 0, stream>>>(el, cnt, slots, E);
  row_kernel<<<Nn / 4, 256, 0, stream>>>(cnt, slots, scores, attw, pv, out);
}

// Round 10
// 35.031 us; speedup vs baseline: 7.2396x; 1.1888x over previous
//
#include <hip/hip_runtime.h>

#define NEG_SLOPE_F 0.2f

static constexpr int Nn = 4096;   // nodes
static constexpr int Tt = 3;      // edge types
static constexpr int Dd = 16;     // emb dim
static constexpr int Hh = 4;      // heads
static constexpr int CAP = 256;   // max distinct neighbors per row (E[deg]≈96)
static constexpr int WPR = 128;   // 32-bit words per row per type (4096/32)

__device__ __forceinline__ float waveMax(float v) {
#pragma unroll
  for (int m = 1; m < 64; m <<= 1) v = fmaxf(v, __shfl_xor(v, m));
  return v;
}
__device__ __forceinline__ float waveSum(float v) {
#pragma unroll
  for (int m = 1; m < 64; m <<= 1) v += __shfl_xor(v, m);
  return v;
}

// ---- kernel 1: zero the 6 MB bitmap (wide grid-stride stores); block 0 also
// computes pv[0..11] = c[h][t] and pv[12] = sum(scores) ----
__global__ void clear_prep_kernel(uint4* __restrict__ bm4,
                                  const float* __restrict__ scores,
                                  const float* __restrict__ emb,
                                  const float* __restrict__ attw,
                                  float* __restrict__ pv) {
  const int total = Nn * 3 * WPR / 4;  // 393216 uint4
  uint4 z = make_uint4(0u, 0u, 0u, 0u);
  for (int k = blockIdx.x * 256 + threadIdx.x; k < total; k += gridDim.x * 256)
    bm4[k] = z;
  if (blockIdx.x == 0) {
    __shared__ float rb[4];
    int tid = threadIdx.x;
    float s = 0.f;
    for (int j = tid; j < Nn; j += 256) s += scores[j];
    s = waveSum(s);
    if ((tid & 63) == 0) rb[tid >> 6] = s;
    __syncthreads();
    if (tid == 0) pv[12] = rb[0] + rb[1] + rb[2] + rb[3];
    if (tid < Hh * Tt) {
      int h = tid / Tt, t = tid % Tt;
      float c = 0.f;
#pragma unroll
      for (int d = 0; d < Dd; ++d)
        c += emb[t * Dd + d] * attw[h * (Dd + 2) + 1 + d];
      pv[tid] = c;
    }
  }
}

// ---- kernel 2: fire-and-forget bit atomicOr, ONE atomic per thread ----
// (z-dim = direction; halves per-thread atomic issue/drain dependency)
// bitmap layout: word[(row*3 + t)*WPR + (col>>5)], bit = col&31
__global__ void or_kernel(const int* __restrict__ el,
                          unsigned int* __restrict__ bitmap, int E) {
  int e = blockIdx.x * blockDim.x + threadIdx.x;
  if (e >= E) return;
  int t = blockIdx.y;
  int dir = blockIdx.z;
  unsigned int a = (unsigned int)el[(t * 2 + dir) * E + e];
  unsigned int b = (unsigned int)el[(t * 2 + (1 - dir)) * E + e];
  atomicOr(&bitmap[(a * 3u + t) * WPR + (b >> 5)], 1u << (b & 31u));
}

// ---- kernel 3: one wave per row — extract packed (j|m<<12) pairs from the
// bitmap into wave-private LDS (no barrier needed), then softmax-aggregate ----
__launch_bounds__(256)
__global__ void row_kernel(const unsigned int* __restrict__ bitmap,
                           const float* __restrict__ scores,
                           const float* __restrict__ attw,
                           const float* __restrict__ pv,
                           float* __restrict__ out) {
  __shared__ unsigned short lst[4][CAP];  // 2 KiB, wave-private slices
  int wid = threadIdx.x >> 6, lane = threadIdx.x & 63;
  int i = blockIdx.x * 4 + wid;
  const unsigned int* bm = bitmap + (size_t)i * 3 * WPR;

  // read this row's 6 words per lane (2 word-blocks x 3 types), coalesced
  unsigned int w[2][3];
#pragma unroll
  for (int p = 0; p < 2; ++p)
#pragma unroll
    for (int t = 0; t < 3; ++t) w[p][t] = bm[t * WPR + p * 64 + lane];
  unsigned int orw[2];
  orw[0] = w[0][0] | w[0][1] | w[0][2];
  orw[1] = w[1][0] | w[1][1] | w[1][2];
  int c = __popc(orw[0]) + __popc(orw[1]);
  // inclusive wave scan -> per-lane output offsets
  int off = c;
#pragma unroll
  for (int d = 1; d < 64; d <<= 1) {
    int tv = __shfl_up(off, d);
    if (lane >= d) off += tv;
  }
  int n = __shfl(off, 63);  // row degree (distinct neighbors)
  off -= c;                 // exclusive
  if (n > CAP) n = CAP;
  int idx = off;
#pragma unroll
  for (int p = 0; p < 2; ++p) {
    unsigned int o = orw[p];
    int jbase = (p * 64 + lane) * 32;
    while (o) {
      int b = __ffs(o) - 1;
      o &= o - 1;
      unsigned int m = ((w[p][0] >> b) & 1u) | (((w[p][1] >> b) & 1u) << 1) |
                       (((w[p][2] >> b) & 1u) << 2);
      if (idx < CAP) lst[wid][idx] = (unsigned short)((jbase + b) | (m << 12));
      ++idx;
    }
  }
  // NOTE: no __syncthreads needed — lst[wid] is produced and consumed by the
  // same wave; compiler-inserted lgkmcnt waits order the LDS RAW dependence.

  float si = scores[i];
  float wsrc[Hh], wtgt[Hh], c0[Hh], c1[Hh], c2[Hh];
#pragma unroll
  for (int h = 0; h < Hh; ++h) {
    wsrc[h] = attw[h * (Dd + 2) + 0];
    wtgt[h] = attw[h * (Dd + 2) + Dd + 1];
    c0[h] = pv[h * 3 + 0];
    c1[h] = pv[h * 3 + 1];
    c2[h] = pv[h * 3 + 2];
  }
  float Ssum = pv[12];

  constexpr int IT = CAP / 64;  // 4
  float lv[IT][Hh], sjv[IT];
  float mx[Hh];
#pragma unroll
  for (int h = 0; h < Hh; ++h) mx[h] = -INFINITY;
  float sedge = 0.f;

#pragma unroll
  for (int it = 0; it < IT; ++it) {
    if (it * 64 >= n) break;  // wave-uniform early-out
    int k = it * 64 + lane;
    bool act = k < n;
    unsigned int v = act ? (unsigned int)lst[wid][k] : 0u;
    int j = (int)(v & 0xFFFu);
    int m = act ? (int)(v >> 12) : 0;
    float sj = act ? scores[j] : 0.f;
    sjv[it] = sj;
    if (act) sedge += sj;
    float na = (float)__popc(m);
    float et0 = (m & 1) ? 1.f : 0.f;
    float et1 = (m & 2) ? 1.f : 0.f;
    float et2 = (m & 4) ? 1.f : 0.f;
#pragma unroll
    for (int h = 0; h < Hh; ++h) {
      float et = et0 * c0[h] + et1 * c1[h] + et2 * c2[h];
      float l = na * (wsrc[h] * si + wtgt[h] * sj) + et;
      l = (l >= 0.f) ? l : NEG_SLOPE_F * l;
      lv[it][h] = act ? l : -INFINITY;
      mx[h] = fmaxf(mx[h], lv[it][h]);
    }
  }

#pragma unroll
  for (int h = 0; h < Hh; ++h) {
    mx[h] = waveMax(mx[h]);
    if (n < Nn) mx[h] = fmaxf(mx[h], 0.f);  // non-edge cells contribute logit 0
  }

  float se[Hh], ss[Hh];
#pragma unroll
  for (int h = 0; h < Hh; ++h) { se[h] = 0.f; ss[h] = 0.f; }
#pragma unroll
  for (int it = 0; it < IT; ++it) {
    if (it * 64 >= n) break;
#pragma unroll
    for (int h = 0; h < Hh; ++h) {
      float ex = expf(lv[it][h] - mx[h]);  // inactive lanes: exp(-inf)=0
      se[h] += ex;
      ss[h] += ex * sjv[it];
    }
  }
  sedge = waveSum(sedge);
#pragma unroll
  for (int h = 0; h < Hh; ++h) {
    se[h] = waveSum(se[h]);
    ss[h] = waveSum(ss[h]);
  }
  if (lane == 0) {
    float acc = 0.f;
#pragma unroll
    for (int h = 0; h < Hh; ++h) {
      float nz = expf(-mx[h]);  // exp(0 - max) for every non-edge cell
      float denom = se[h] + nz * ((float)Nn - (float)n);
      float numer = ss[h] + nz * (Ssum - sedge);
      acc += numer / denom;
    }
    out[i] = acc * (1.f / (float)Hh);
  }
}

extern "C" void kernel_launch(void* const* d_in, const int* in_sizes, int n_in,
                              void* d_out, int out_size, void* d_ws, size_t ws_size,
                              hipStream_t stream) {
  const float* scores = (const float*)d_in[0];
  const float* emb    = (const float*)d_in[1];
  const float* attw   = (const float*)d_in[2];
  const int*   el     = (const int*)d_in[3];
  float* out = (float*)d_out;
  int E = in_sizes[3] / (Tt * 2);

  // ws layout: [bitmap 6MB][pv 64B]
  size_t bm_bytes = (size_t)Nn * 3 * WPR * 4;  // 6 MiB
  unsigned int* bitmap = (unsigned int*)d_ws;
  float* pv = (float*)((char*)d_ws + bm_bytes);

  clear_prep_kernel<<<768, 256, 0, stream>>>((uint4*)d_ws, scores, emb, attw, pv);
  or_kernel<<<dim3((E + 255) / 256, Tt, 2), 256, 0, stream>>>(el, bitmap, E);
  row_kernel<<<Nn / 4, 256, 0, stream>>>(bitmap, scores, attw, pv, out);
}